// Round 2
// baseline (310.074 us; speedup 1.0000x reference)
//
#include <hip/hip_runtime.h>

// ---------- types ----------
typedef __bf16 bf16x8 __attribute__((ext_vector_type(8)));
typedef float  f32x4  __attribute__((ext_vector_type(4)));

__device__ __forceinline__ unsigned short f2bf(float f) {
    union { float f; unsigned int u; } x; x.f = f;
    unsigned int r = (x.u + 0x7FFFu + ((x.u >> 16) & 1u)) >> 16;  // RNE
    return (unsigned short)r;
}

// ==========================================================================
// GEMM: C[m][n] = alpha * sum_k A[m][k]*B[k][n] (+bias[m]) (+resid)
// A stored [m][k] k-contiguous, B stored [n][k] k-contiguous.
// TRANS_OUT: store C transposed as C[n][m].
// 128x128 tile, BK=32, 256 threads = 4 waves (2x2), wave tile 64x64.
// ==========================================================================
template<typename OutT, bool TRANS_OUT, bool HAS_BIAS, bool HAS_RESID>
__global__ __launch_bounds__(256) void gemm_k(
    const unsigned short* __restrict__ Ag, long sA, int lda,
    const unsigned short* __restrict__ Bg, long sB, int ldb,
    OutT* __restrict__ Cg, long sC, int ldc,
    const float* __restrict__ bias,
    const float* __restrict__ resid, long sR,
    float alpha, int K)
{
    __shared__ __align__(16) unsigned short As[128 * 40];
    __shared__ __align__(16) unsigned short Bs[128 * 40];

    const int tid  = threadIdx.x;
    const int lane = tid & 63;
    const int wave = tid >> 6;
    const int wm   = (wave >> 1) * 64;
    const int wn   = (wave & 1) * 64;
    const int l16  = lane & 15;
    const int quad = lane >> 4;

    const unsigned short* Ab = Ag + (long)blockIdx.z * sA + (long)(blockIdx.y * 128) * lda;
    const unsigned short* Bb = Bg + (long)blockIdx.z * sB + (long)(blockIdx.x * 128) * ldb;

    const int sm = tid >> 2;
    const int sk = (tid & 3) * 8;

    f32x4 acc[4][4] = {};

    for (int k0 = 0; k0 < K; k0 += 32) {
        uint4 a0 = *(const uint4*)(Ab + (long)sm * lda + k0 + sk);
        uint4 a1 = *(const uint4*)(Ab + (long)(sm + 64) * lda + k0 + sk);
        uint4 b0 = *(const uint4*)(Bb + (long)sm * ldb + k0 + sk);
        uint4 b1 = *(const uint4*)(Bb + (long)(sm + 64) * ldb + k0 + sk);
        __syncthreads();
        *(uint4*)&As[sm * 40 + sk]        = a0;
        *(uint4*)&As[(sm + 64) * 40 + sk] = a1;
        *(uint4*)&Bs[sm * 40 + sk]        = b0;
        *(uint4*)&Bs[(sm + 64) * 40 + sk] = b1;
        __syncthreads();

        bf16x8 af[4], bfr[4];
        #pragma unroll
        for (int mi = 0; mi < 4; mi++)
            af[mi] = *(const bf16x8*)&As[(wm + mi * 16 + l16) * 40 + quad * 8];
        #pragma unroll
        for (int ni = 0; ni < 4; ni++)
            bfr[ni] = *(const bf16x8*)&Bs[(wn + ni * 16 + l16) * 40 + quad * 8];
        #pragma unroll
        for (int mi = 0; mi < 4; mi++)
            #pragma unroll
            for (int ni = 0; ni < 4; ni++)
                acc[mi][ni] = __builtin_amdgcn_mfma_f32_16x16x32_bf16(af[mi], bfr[ni], acc[mi][ni], 0, 0, 0);
    }

    const int mb = blockIdx.y * 128 + wm;
    const int nb = blockIdx.x * 128 + wn;
    #pragma unroll
    for (int mi = 0; mi < 4; mi++) {
        #pragma unroll
        for (int ni = 0; ni < 4; ni++) {
            f32x4 v = acc[mi][ni];
            const int m0 = mb + mi * 16 + quad * 4;
            const int n  = nb + ni * 16 + l16;
            float o[4];
            #pragma unroll
            for (int r = 0; r < 4; r++) {
                float val = v[r] * alpha;
                if (HAS_BIAS) val += bias[m0 + r];
                o[r] = val;
            }
            if constexpr (!TRANS_OUT) {
                const long base = (long)blockIdx.z * sC;
                #pragma unroll
                for (int r = 0; r < 4; r++) {
                    float val = o[r];
                    if (HAS_RESID) val += resid[(long)blockIdx.z * sR + (long)(m0 + r) * ldc + n];
                    long idx = base + (long)(m0 + r) * ldc + n;
                    if constexpr (sizeof(OutT) == 2) ((unsigned short*)Cg)[idx] = f2bf(val);
                    else                              ((float*)Cg)[idx] = val;
                }
            } else {
                const long idx = (long)blockIdx.z * sC + (long)n * ldc + m0;
                if constexpr (sizeof(OutT) == 2) {
                    ushort4 p; p.x = f2bf(o[0]); p.y = f2bf(o[1]); p.z = f2bf(o[2]); p.w = f2bf(o[3]);
                    *(ushort4*)((unsigned short*)Cg + idx) = p;
                } else {
                    float4 p; p.x = o[0]; p.y = o[1]; p.z = o[2]; p.w = o[3];
                    *(float4*)((float*)Cg + idx) = p;
                }
            }
        }
    }
}

// ==========================================================================
// Flash attention: qT[b][i][c], kT[b][j][c], vB[b][c][j] -> OT[b][i][c]
// block = 32 Q-rows, 256 threads (4 waves). j in tiles of 256 (4 iters).
// S^T = K·Q (M=j per-wave 64, N=i 32); online softmax (i on lane&15);
// P -> LDS [i][j]; O = V·P (M=c per-wave 128, N=i 32) accum in regs.
// K,V fragments loaded directly global->VGPR (each element used once/block).
// ==========================================================================
__global__ __launch_bounds__(256, 2) void flash_k(
    const unsigned short* __restrict__ qT,
    const unsigned short* __restrict__ kT,
    const unsigned short* __restrict__ vB,
    unsigned short* __restrict__ OT)
{
    constexpr int QPAD = 520, PPAD = 264;
    __shared__ __align__(16) unsigned short Qs[32 * QPAD];   // 33.3 KB
    __shared__ __align__(16) unsigned short Ps[32 * PPAD];   // 16.9 KB
    __shared__ float redM[4][32];
    __shared__ float redS[4][32];

    const int b   = blockIdx.y;
    const int i0  = blockIdx.x * 32;
    const int tid = threadIdx.x;
    const int w    = tid >> 6;
    const int lane = tid & 63;
    const int l16  = lane & 15;
    const int quad = lane >> 4;

    const unsigned short* qb = qT + ((long)b * 1024 + i0) * 512;
    const unsigned short* kb = kT + (long)b * 524288;
    const unsigned short* vb = vB + (long)b * 524288;

    // stage Q tile (32 x 512)
    {
        const int r = tid >> 3, ch = tid & 7;
        const uint4* src = (const uint4*)(qb + (long)r * 512);
        uint4* dst = (uint4*)&Qs[r * QPAD];
        #pragma unroll
        for (int rep = 0; rep < 8; rep++)
            dst[ch + rep * 8] = src[ch + rep * 8];
    }
    __syncthreads();

    const float scale = 0.044194173824159216f;  // 512^-0.5
    float mrun[2] = {-1e30f, -1e30f};
    float lrun[2] = {0.f, 0.f};
    f32x4 oacc[8][2] = {};

    for (int jt = 0; jt < 4; jt++) {
        const int j0 = jt * 256;

        // ---- QK^T: S^T[j][i], K-reduction over c=512 ----
        f32x4 sacc[4][2] = {};
        const unsigned short* krow = kb + (long)(j0 + w * 64 + l16) * 512 + quad * 8;
        #pragma unroll 4
        for (int k0 = 0; k0 < 512; k0 += 32) {
            bf16x8 kf[4], qf[2];
            #pragma unroll
            for (int mt = 0; mt < 4; mt++)
                kf[mt] = *(const bf16x8*)(krow + (long)mt * 16 * 512 + k0);
            #pragma unroll
            for (int nt = 0; nt < 2; nt++)
                qf[nt] = *(const bf16x8*)&Qs[(nt * 16 + l16) * QPAD + k0 + quad * 8];
            #pragma unroll
            for (int mt = 0; mt < 4; mt++)
                #pragma unroll
                for (int nt = 0; nt < 2; nt++)
                    sacc[mt][nt] = __builtin_amdgcn_mfma_f32_16x16x32_bf16(kf[mt], qf[nt], sacc[mt][nt], 0, 0, 0);
        }

        // ---- scale + per-i partial max (i = nt*16 + l16) ----
        float pmax[2] = {-1e30f, -1e30f};
        #pragma unroll
        for (int mt = 0; mt < 4; mt++)
            #pragma unroll
            for (int nt = 0; nt < 2; nt++) {
                f32x4 v = sacc[mt][nt];
                v[0] *= scale; v[1] *= scale; v[2] *= scale; v[3] *= scale;
                sacc[mt][nt] = v;
                pmax[nt] = fmaxf(pmax[nt], fmaxf(fmaxf(v[0], v[1]), fmaxf(v[2], v[3])));
            }
        #pragma unroll
        for (int nt = 0; nt < 2; nt++) {
            pmax[nt] = fmaxf(pmax[nt], __shfl_xor(pmax[nt], 16));
            pmax[nt] = fmaxf(pmax[nt], __shfl_xor(pmax[nt], 32));
        }
        __syncthreads();                       // A: prior iter's Ps/red reads complete
        if (quad == 0) { redM[w][l16] = pmax[0]; redM[w][16 + l16] = pmax[1]; }
        __syncthreads();                       // B

        float mnew[2], alpha[2];
        #pragma unroll
        for (int nt = 0; nt < 2; nt++) {
            const int i = nt * 16 + l16;
            float tm = fmaxf(fmaxf(redM[0][i], redM[1][i]), fmaxf(redM[2][i], redM[3][i]));
            mnew[nt]  = fmaxf(mrun[nt], tm);
            alpha[nt] = __expf(mrun[nt] - mnew[nt]);
            mrun[nt]  = mnew[nt];
        }

        // ---- P = exp(S - m), store to Ps[i][j], partial row sums ----
        float psum[2] = {0.f, 0.f};
        #pragma unroll
        for (int mt = 0; mt < 4; mt++)
            #pragma unroll
            for (int nt = 0; nt < 2; nt++) {
                f32x4 v = sacc[mt][nt];
                float e0 = __expf(v[0] - mnew[nt]);
                float e1 = __expf(v[1] - mnew[nt]);
                float e2 = __expf(v[2] - mnew[nt]);
                float e3 = __expf(v[3] - mnew[nt]);
                psum[nt] += (e0 + e1) + (e2 + e3);
                ushort4 p; p.x = f2bf(e0); p.y = f2bf(e1); p.z = f2bf(e2); p.w = f2bf(e3);
                *(ushort4*)&Ps[(nt * 16 + l16) * PPAD + w * 64 + mt * 16 + quad * 4] = p;
            }
        #pragma unroll
        for (int nt = 0; nt < 2; nt++) {
            psum[nt] += __shfl_xor(psum[nt], 16);
            psum[nt] += __shfl_xor(psum[nt], 32);
        }
        if (quad == 0) { redS[w][l16] = psum[0]; redS[w][16 + l16] = psum[1]; }
        __syncthreads();                       // C: Ps + redS visible

        #pragma unroll
        for (int nt = 0; nt < 2; nt++) {
            const int i = nt * 16 + l16;
            lrun[nt] = lrun[nt] * alpha[nt] +
                       ((redS[0][i] + redS[1][i]) + (redS[2][i] + redS[3][i]));
        }
        #pragma unroll
        for (int mt = 0; mt < 8; mt++)
            #pragma unroll
            for (int nt = 0; nt < 2; nt++)
                oacc[mt][nt] *= alpha[nt];

        // ---- PV: O[c][i] += V[c][j] * P[i][j], K-reduction over j=256 ----
        const unsigned short* vrow = vb + (long)(w * 128 + l16) * 1024 + j0 + quad * 8;
        #pragma unroll 2
        for (int k0 = 0; k0 < 256; k0 += 32) {
            bf16x8 vf[8], pf[2];
            #pragma unroll
            for (int mt = 0; mt < 8; mt++)
                vf[mt] = *(const bf16x8*)(vrow + (long)mt * 16 * 1024 + k0);
            #pragma unroll
            for (int nt = 0; nt < 2; nt++)
                pf[nt] = *(const bf16x8*)&Ps[(nt * 16 + l16) * PPAD + k0 + quad * 8];
            #pragma unroll
            for (int mt = 0; mt < 8; mt++)
                #pragma unroll
                for (int nt = 0; nt < 2; nt++)
                    oacc[mt][nt] = __builtin_amdgcn_mfma_f32_16x16x32_bf16(vf[mt], pf[nt], oacc[mt][nt], 0, 0, 0);
        }
    }

    // ---- epilogue: OT[i][c] = O[c][i] / l[i] ----
    unsigned short* ob = OT + ((long)b * 1024 + i0) * 512;
    #pragma unroll
    for (int nt = 0; nt < 2; nt++) {
        const float invl = 1.f / lrun[nt];
        const int i = nt * 16 + l16;
        #pragma unroll
        for (int mt = 0; mt < 8; mt++) {
            f32x4 v = oacc[mt][nt];
            ushort4 p;
            p.x = f2bf(v[0] * invl); p.y = f2bf(v[1] * invl);
            p.z = f2bf(v[2] * invl); p.w = f2bf(v[3] * invl);
            *(ushort4*)(ob + (long)i * 512 + w * 128 + mt * 16 + quad * 4) = p;
        }
    }
}

// ==========================================================================
// GroupNorm: x[b][c][n] (fp32) -> xnT[b][n][c] (bf16), 32 groups of 16 ch
// ==========================================================================
__global__ __launch_bounds__(256) void gn_k(
    const float* __restrict__ x, const float* __restrict__ gsc,
    const float* __restrict__ gbi, unsigned short* __restrict__ xnT)
{
    __shared__ __align__(16) unsigned short ln[16 * 1024];
    __shared__ float red[8];
    const int b = blockIdx.y, g = blockIdx.x;
    const int tid = threadIdx.x, lane = tid & 63, wv = tid >> 6;

    const float4* x4 = (const float4*)(x + ((long)b * 512 + g * 16) * 1024);
    float4 vals[16];
    float s = 0.f, ss = 0.f;
    #pragma unroll
    for (int i = 0; i < 16; i++) {
        float4 v = x4[tid + i * 256];
        vals[i] = v;
        s  += v.x + v.y + v.z + v.w;
        ss += v.x * v.x + v.y * v.y + v.z * v.z + v.w * v.w;
    }
    for (int o = 32; o; o >>= 1) { s += __shfl_down(s, o); ss += __shfl_down(ss, o); }
    if (lane == 0) { red[wv * 2] = s; red[wv * 2 + 1] = ss; }
    __syncthreads();
    const float S  = red[0] + red[2] + red[4] + red[6];
    const float SS = red[1] + red[3] + red[5] + red[7];
    const float mean = S * (1.f / 16384.f);
    const float var  = SS * (1.f / 16384.f) - mean * mean;
    const float inv  = rsqrtf(var + 1e-5f);

    #pragma unroll
    for (int i = 0; i < 16; i++) {
        const int idx = tid + i * 256;
        const int c   = idx >> 8;
        const float sc = gsc[g * 16 + c] * inv;
        const float bi = gbi[g * 16 + c] - mean * sc;
        float4 v = vals[i];
        ushort4 p;
        p.x = f2bf(v.x * sc + bi); p.y = f2bf(v.y * sc + bi);
        p.z = f2bf(v.z * sc + bi); p.w = f2bf(v.w * sc + bi);
        ((ushort4*)ln)[idx] = p;
    }
    __syncthreads();

    unsigned short* op = xnT + (long)b * 1024 * 512 + g * 16;
    for (int rep = 0; rep < 4; rep++) {
        const int n = rep * 256 + tid;
        union { unsigned short u[16]; uint4 v[2]; } t;
        #pragma unroll
        for (int c = 0; c < 16; c++) t.u[c] = ln[c * 1024 + n];
        *(uint4*)&op[(long)n * 512]     = t.v[0];
        *(uint4*)&op[(long)n * 512 + 8] = t.v[1];
    }
}

// ---------- weights fp32 -> bf16 (wq|wk|wv|wp concatenated) ----------
__global__ __launch_bounds__(256) void wconv_k(
    const float* __restrict__ w0, const float* __restrict__ w1,
    const float* __restrict__ w2, const float* __restrict__ w3,
    unsigned short* __restrict__ out)
{
    const int m = blockIdx.y;
    const float* src = (m == 0) ? w0 : (m == 1) ? w1 : (m == 2) ? w2 : w3;
    const int i = blockIdx.x * 256 + threadIdx.x;
    float4 v = ((const float4*)src)[i];
    ushort4 o; o.x = f2bf(v.x); o.y = f2bf(v.y); o.z = f2bf(v.z); o.w = f2bf(v.w);
    ((ushort4*)(out + (long)m * 262144))[i] = o;
}

// ==========================================================================
extern "C" void kernel_launch(void* const* d_in, const int* in_sizes, int n_in,
                              void* d_out, int out_size, void* d_ws, size_t ws_size,
                              hipStream_t stream)
{
    const float* x   = (const float*)d_in[0];
    const float* gsc = (const float*)d_in[1];
    const float* gbi = (const float*)d_in[2];
    const float* wq  = (const float*)d_in[3];
    const float* bq  = (const float*)d_in[4];
    const float* wk  = (const float*)d_in[5];
    const float* bk  = (const float*)d_in[6];
    const float* wv  = (const float*)d_in[7];
    const float* bv  = (const float*)d_in[8];
    const float* wp  = (const float*)d_in[9];
    const float* bp  = (const float*)d_in[10];
    float* out = (float*)d_out;

    char* ws = (char*)d_ws;
    unsigned short* xnT = (unsigned short*)(ws);               // 16 MB [b][n][c]; reused as OT
    unsigned short* qT  = (unsigned short*)(ws + 16777216);    // 16 MB [b][i][c]
    unsigned short* kT  = (unsigned short*)(ws + 33554432);    // 16 MB [b][j][c]
    unsigned short* vB  = (unsigned short*)(ws + 50331648);    // 16 MB [b][c][j]
    unsigned short* Wb  = (unsigned short*)(ws + 67108864);    // 2 MB: wq|wk|wv|wp bf16
    unsigned short* OT  = xnT;                                 // alias: xnT dead after QKV

    const long sBCN = 512L * 1024;

    wconv_k<<<dim3(256, 4), 256, 0, stream>>>(wq, wk, wv, wp, Wb);
    gn_k<<<dim3(32, 16), 256, 0, stream>>>(x, gsc, gbi, xnT);

    // Q = Wq * xn -> qT[i][c]
    gemm_k<unsigned short, true, true, false><<<dim3(8, 4, 16), 256, 0, stream>>>(
        Wb, 0, 512, xnT, sBCN, 512, qT, sBCN, 512, bq, nullptr, 0, 1.f, 512);
    // K = Wk * xn -> kT[j][c]
    gemm_k<unsigned short, true, true, false><<<dim3(8, 4, 16), 256, 0, stream>>>(
        Wb + 262144, 0, 512, xnT, sBCN, 512, kT, sBCN, 512, bk, nullptr, 0, 1.f, 512);
    // V = Wv * xn -> vB[c][j]
    gemm_k<unsigned short, false, true, false><<<dim3(8, 4, 16), 256, 0, stream>>>(
        Wb + 524288, 0, 512, xnT, sBCN, 512, vB, sBCN, 1024, bv, nullptr, 0, 1.f, 512);

    // fused S = QK^T / softmax / O = A V  -> OT[i][c]
    flash_k<<<dim3(32, 16), 256, 0, stream>>>(qT, kT, vB, OT);

    // out = Wp * O + bp + x
    gemm_k<float, false, true, true><<<dim3(8, 4, 16), 256, 0, stream>>>(
        Wb + 786432, 0, 512, OT, sBCN, 512, out, sBCN, 1024, bp, x, sBCN, 1.f, 512);
}

// Round 3
// 269.082 us; speedup vs baseline: 1.1523x; 1.1523x over previous
//
#include <hip/hip_runtime.h>

// ---------- types ----------
typedef __bf16 bf16x8 __attribute__((ext_vector_type(8)));
typedef float  f32x4  __attribute__((ext_vector_type(4)));

__device__ __forceinline__ unsigned short f2bf(float f) {
    union { float f; unsigned int u; } x; x.f = f;
    unsigned int r = (x.u + 0x7FFFu + ((x.u >> 16) & 1u)) >> 16;  // RNE
    return (unsigned short)r;
}
__device__ __forceinline__ float bf2f(unsigned int hi) {
    union { unsigned int u; float f; } x; x.u = hi; return x.f;
}

// async global->LDS, 16B per lane; lptr MUST be wave-uniform (dst = base + lane*16)
typedef const __attribute__((address_space(1))) unsigned short gu16;
typedef __attribute__((address_space(3)))       unsigned short lu16;
__device__ __forceinline__ void gl_lds16(const unsigned short* g, unsigned short* l) {
    __builtin_amdgcn_global_load_lds((gu16*)g, (lu16*)l, 16, 0, 0);
}

// ==========================================================================
// GEMM (m97-style): C[m][n] = alpha*sum_k A[m][k]*B[k][n] (+bias[m]) (+resid)
// A [m][k] k-contig (lda), B [n][k] k-contig (ldb). TRANS_OUT: C[n][m].
// 128x128 tile, BK=32, 256 thr = 4 waves (2x2), wave 64x64 (4x4 MFMA tiles).
// Staging: global_load_lds width-16 into UNPADDED [128][32] LDS (lane-order
// contiguous — required by wave-uniform LDS base). 2-barrier K-loop.
// ==========================================================================
template<typename OutT, bool TRANS_OUT, bool HAS_BIAS, bool HAS_RESID>
__global__ __launch_bounds__(256) void gemm_k(
    const unsigned short* __restrict__ Ag, long sA, int lda,
    const unsigned short* __restrict__ Bg, long sB, int ldb,
    OutT* __restrict__ Cg, long sC, int ldc,
    const float* __restrict__ bias,
    const float* __restrict__ resid, long sR,
    float alpha, int K)
{
    __shared__ __align__(16) unsigned short As[128 * 32];  // 8 KB, no pad
    __shared__ __align__(16) unsigned short Bs[128 * 32];

    const int tid  = threadIdx.x;
    const int lane = tid & 63;
    const int wave = tid >> 6;
    const int wm   = (wave >> 1) * 64;
    const int wn   = (wave & 1) * 64;
    const int l16  = lane & 15;
    const int quad = lane >> 4;

    const unsigned short* Ab = Ag + (long)blockIdx.z * sA + (long)(blockIdx.y * 128) * lda;
    const unsigned short* Bb = Bg + (long)blockIdx.z * sB + (long)(blockIdx.x * 128) * ldb;

    // staging map: p = i*256 + wave*64 + lane (16B units); row=p/4, col16=(p%4)
    const int r0 = wave * 16 + (lane >> 2);
    const int c0 = (lane & 3) * 8;
    const unsigned short* gA0 = Ab + (long)r0 * lda + c0;
    const unsigned short* gA1 = gA0 + 64L * lda;
    const unsigned short* gB0 = Bb + (long)r0 * ldb + c0;
    const unsigned short* gB1 = gB0 + 64L * ldb;
    unsigned short* lA0 = As + wave * 512;          // i=0: elem base (0*2048 + w*512)
    unsigned short* lA1 = As + 2048 + wave * 512;   // i=1
    unsigned short* lB0 = Bs + wave * 512;
    unsigned short* lB1 = Bs + 2048 + wave * 512;

    f32x4 acc[4][4] = {};

    for (int k0 = 0; k0 < K; k0 += 32) {
        __syncthreads();                 // all waves done reading prev tile
        gl_lds16(gA0 + k0, lA0);
        gl_lds16(gA1 + k0, lA1);
        gl_lds16(gB0 + k0, lB0);
        gl_lds16(gB1 + k0, lB1);
        __syncthreads();                 // implicit vmcnt(0) drain -> tile visible

        bf16x8 af[4], bfr[4];
        #pragma unroll
        for (int mi = 0; mi < 4; mi++)
            af[mi] = *(const bf16x8*)&As[(wm + mi * 16 + l16) * 32 + quad * 8];
        #pragma unroll
        for (int ni = 0; ni < 4; ni++)
            bfr[ni] = *(const bf16x8*)&Bs[(wn + ni * 16 + l16) * 32 + quad * 8];
        #pragma unroll
        for (int mi = 0; mi < 4; mi++)
            #pragma unroll
            for (int ni = 0; ni < 4; ni++)
                acc[mi][ni] = __builtin_amdgcn_mfma_f32_16x16x32_bf16(af[mi], bfr[ni], acc[mi][ni], 0, 0, 0);
    }

    const int mb = blockIdx.y * 128 + wm;
    const int nb = blockIdx.x * 128 + wn;
    #pragma unroll
    for (int mi = 0; mi < 4; mi++) {
        #pragma unroll
        for (int ni = 0; ni < 4; ni++) {
            f32x4 v = acc[mi][ni];
            const int m0 = mb + mi * 16 + quad * 4;
            const int n  = nb + ni * 16 + l16;
            float o[4];
            #pragma unroll
            for (int r = 0; r < 4; r++) {
                float val = v[r] * alpha;
                if (HAS_BIAS) val += bias[m0 + r];
                o[r] = val;
            }
            if constexpr (!TRANS_OUT) {
                const long base = (long)blockIdx.z * sC;
                #pragma unroll
                for (int r = 0; r < 4; r++) {
                    float val = o[r];
                    if (HAS_RESID) val += resid[(long)blockIdx.z * sR + (long)(m0 + r) * ldc + n];
                    long idx = base + (long)(m0 + r) * ldc + n;
                    if constexpr (sizeof(OutT) == 2) ((unsigned short*)Cg)[idx] = f2bf(val);
                    else                              ((float*)Cg)[idx] = val;
                }
            } else {
                const long idx = (long)blockIdx.z * sC + (long)n * ldc + m0;
                if constexpr (sizeof(OutT) == 2) {
                    ushort4 p; p.x = f2bf(o[0]); p.y = f2bf(o[1]); p.z = f2bf(o[2]); p.w = f2bf(o[3]);
                    *(ushort4*)((unsigned short*)Cg + idx) = p;
                } else {
                    float4 p; p.x = o[0]; p.y = o[1]; p.z = o[2]; p.w = o[3];
                    *(float4*)((float*)Cg + idx) = p;
                }
            }
        }
    }
}

// ==========================================================================
// Softmax over rows of S (bf16 [16][1024][1024], in place). Scale already
// folded into the S GEMM. fp32 math internally.
// ==========================================================================
__global__ __launch_bounds__(256) void softmax_k(unsigned short* __restrict__ S)
{
    __shared__ float red[4];
    const long row = (long)blockIdx.y * 1024 + blockIdx.x;
    unsigned short* sp = S + row * 1024;
    const int tid = threadIdx.x, lane = tid & 63, wv = tid >> 6;

    uint2 u = ((const uint2*)sp)[tid];               // 4 bf16
    float f0 = bf2f(u.x << 16), f1 = bf2f(u.x & 0xFFFF0000u);
    float f2 = bf2f(u.y << 16), f3 = bf2f(u.y & 0xFFFF0000u);

    float mx = fmaxf(fmaxf(f0, f1), fmaxf(f2, f3));
    for (int o = 32; o; o >>= 1) mx = fmaxf(mx, __shfl_down(mx, o));
    if (lane == 0) red[wv] = mx;
    __syncthreads();
    mx = fmaxf(fmaxf(red[0], red[1]), fmaxf(red[2], red[3]));

    float e0 = __expf(f0 - mx), e1 = __expf(f1 - mx);
    float e2 = __expf(f2 - mx), e3 = __expf(f3 - mx);
    float sum = (e0 + e1) + (e2 + e3);
    for (int o = 32; o; o >>= 1) sum += __shfl_down(sum, o);
    __syncthreads();
    if (lane == 0) red[wv] = sum;
    __syncthreads();
    const float inv = 1.f / (red[0] + red[1] + red[2] + red[3]);

    ushort4 o4;
    o4.x = f2bf(e0 * inv); o4.y = f2bf(e1 * inv);
    o4.z = f2bf(e2 * inv); o4.w = f2bf(e3 * inv);
    ((ushort4*)sp)[tid] = o4;
}

// ==========================================================================
// GroupNorm: x[b][c][n] (fp32) -> xnT[b][n][c] (bf16), 32 groups of 16 ch
// ==========================================================================
__global__ __launch_bounds__(256) void gn_k(
    const float* __restrict__ x, const float* __restrict__ gsc,
    const float* __restrict__ gbi, unsigned short* __restrict__ xnT)
{
    __shared__ __align__(16) unsigned short ln[16 * 1024];
    __shared__ float red[8];
    const int b = blockIdx.y, g = blockIdx.x;
    const int tid = threadIdx.x, lane = tid & 63, wv = tid >> 6;

    const float4* x4 = (const float4*)(x + ((long)b * 512 + g * 16) * 1024);
    float4 vals[16];
    float s = 0.f, ss = 0.f;
    #pragma unroll
    for (int i = 0; i < 16; i++) {
        float4 v = x4[tid + i * 256];
        vals[i] = v;
        s  += v.x + v.y + v.z + v.w;
        ss += v.x * v.x + v.y * v.y + v.z * v.z + v.w * v.w;
    }
    for (int o = 32; o; o >>= 1) { s += __shfl_down(s, o); ss += __shfl_down(ss, o); }
    if (lane == 0) { red[wv * 2] = s; red[wv * 2 + 1] = ss; }
    __syncthreads();
    const float S  = red[0] + red[2] + red[4] + red[6];
    const float SS = red[1] + red[3] + red[5] + red[7];
    const float mean = S * (1.f / 16384.f);
    const float var  = SS * (1.f / 16384.f) - mean * mean;
    const float inv  = rsqrtf(var + 1e-5f);

    #pragma unroll
    for (int i = 0; i < 16; i++) {
        const int idx = tid + i * 256;
        const int c   = idx >> 8;
        const float sc = gsc[g * 16 + c] * inv;
        const float bi = gbi[g * 16 + c] - mean * sc;
        float4 v = vals[i];
        ushort4 p;
        p.x = f2bf(v.x * sc + bi); p.y = f2bf(v.y * sc + bi);
        p.z = f2bf(v.z * sc + bi); p.w = f2bf(v.w * sc + bi);
        ((ushort4*)ln)[idx] = p;
    }
    __syncthreads();

    unsigned short* op = xnT + (long)b * 1024 * 512 + g * 16;
    for (int rep = 0; rep < 4; rep++) {
        const int n = rep * 256 + tid;
        union { unsigned short u[16]; uint4 v[2]; } t;
        #pragma unroll
        for (int c = 0; c < 16; c++) t.u[c] = ln[c * 1024 + n];
        *(uint4*)&op[(long)n * 512]     = t.v[0];
        *(uint4*)&op[(long)n * 512 + 8] = t.v[1];
    }
}

// ---------- weights fp32 -> bf16 (wq|wk|wv|wp concatenated) ----------
__global__ __launch_bounds__(256) void wconv_k(
    const float* __restrict__ w0, const float* __restrict__ w1,
    const float* __restrict__ w2, const float* __restrict__ w3,
    unsigned short* __restrict__ out)
{
    const int m = blockIdx.y;
    const float* src = (m == 0) ? w0 : (m == 1) ? w1 : (m == 2) ? w2 : w3;
    const int i = blockIdx.x * 256 + threadIdx.x;
    float4 v = ((const float4*)src)[i];
    ushort4 o; o.x = f2bf(v.x); o.y = f2bf(v.y); o.z = f2bf(v.z); o.w = f2bf(v.w);
    ((ushort4*)(out + (long)m * 262144))[i] = o;
}

// ==========================================================================
extern "C" void kernel_launch(void* const* d_in, const int* in_sizes, int n_in,
                              void* d_out, int out_size, void* d_ws, size_t ws_size,
                              hipStream_t stream)
{
    const float* x   = (const float*)d_in[0];
    const float* gsc = (const float*)d_in[1];
    const float* gbi = (const float*)d_in[2];
    const float* wq  = (const float*)d_in[3];
    const float* bq  = (const float*)d_in[4];
    const float* wk  = (const float*)d_in[5];
    const float* bk  = (const float*)d_in[6];
    const float* wv  = (const float*)d_in[7];
    const float* bv  = (const float*)d_in[8];
    const float* wp  = (const float*)d_in[9];
    const float* bp  = (const float*)d_in[10];
    float* out = (float*)d_out;

    char* ws = (char*)d_ws;
    unsigned short* xnT = (unsigned short*)(ws);               // 16 MB [b][n][c]; reused as OT
    unsigned short* qT  = (unsigned short*)(ws + 16777216);    // 16 MB [b][i][c]
    unsigned short* kT  = (unsigned short*)(ws + 33554432);    // 16 MB [b][j][c]
    unsigned short* vB  = (unsigned short*)(ws + 50331648);    // 16 MB [b][c][j]
    unsigned short* Sb  = (unsigned short*)(ws + 67108864);    // 32 MB [b][i][j] bf16
    unsigned short* Wb  = (unsigned short*)(ws + 100663296);   // 2 MB: wq|wk|wv|wp bf16
    unsigned short* OT  = xnT;                                 // alias: xnT dead after QKV

    const long sBCN = 512L * 1024;

    wconv_k<<<dim3(256, 4), 256, 0, stream>>>(wq, wk, wv, wp, Wb);
    gn_k<<<dim3(32, 16), 256, 0, stream>>>(x, gsc, gbi, xnT);

    // Q = Wq * xn -> qT[i][c]
    gemm_k<unsigned short, true, true, false><<<dim3(8, 4, 16), 256, 0, stream>>>(
        Wb, 0, 512, xnT, sBCN, 512, qT, sBCN, 512, bq, nullptr, 0, 1.f, 512);
    // K = Wk * xn -> kT[j][c]
    gemm_k<unsigned short, true, true, false><<<dim3(8, 4, 16), 256, 0, stream>>>(
        Wb + 262144, 0, 512, xnT, sBCN, 512, kT, sBCN, 512, bk, nullptr, 0, 1.f, 512);
    // V = Wv * xn -> vB[c][j]
    gemm_k<unsigned short, false, true, false><<<dim3(8, 4, 16), 256, 0, stream>>>(
        Wb + 524288, 0, 512, xnT, sBCN, 512, vB, sBCN, 1024, bv, nullptr, 0, 1.f, 512);

    // S[i][j] = (1/sqrt(512)) * q·k  -> bf16
    gemm_k<unsigned short, false, false, false><<<dim3(8, 8, 16), 256, 0, stream>>>(
        qT, sBCN, 512, kT, sBCN, 512, Sb, 1048576L, 1024, nullptr, nullptr, 0,
        0.044194173824159216f, 512);
    softmax_k<<<dim3(1024, 16), 256, 0, stream>>>(Sb);
    // O[c][i] = sum_j v[c][j]*A[i][j] -> OT[i][c]
    gemm_k<unsigned short, true, false, false><<<dim3(8, 4, 16), 256, 0, stream>>>(
        vB, sBCN, 1024, Sb, 1048576L, 1024, OT, sBCN, 512,
        nullptr, nullptr, 0, 1.f, 1024);
    // out = Wp * O + bp + x
    gemm_k<float, false, true, true><<<dim3(8, 4, 16), 256, 0, stream>>>(
        Wb + 786432, 0, 512, OT, sBCN, 512, out, sBCN, 1024, bp, x, sBCN, 1.f, 512);
}

// Round 4
// 259.130 us; speedup vs baseline: 1.1966x; 1.0384x over previous
//
#include <hip/hip_runtime.h>

// ---------- types ----------
typedef __bf16 bf16x8 __attribute__((ext_vector_type(8)));
typedef float  f32x4  __attribute__((ext_vector_type(4)));

__device__ __forceinline__ unsigned short f2bf(float f) {
    union { float f; unsigned int u; } x; x.f = f;
    unsigned int r = (x.u + 0x7FFFu + ((x.u >> 16) & 1u)) >> 16;  // RNE
    return (unsigned short)r;
}
__device__ __forceinline__ float bf2f(unsigned int hi) {
    union { unsigned int u; float f; } x; x.u = hi; return x.f;
}

// async global->LDS, 16B per lane; LDS dst is wave-uniform base + lane*16
typedef const __attribute__((address_space(1))) unsigned short gu16;
typedef __attribute__((address_space(3)))       unsigned short lu16;
__device__ __forceinline__ void gl_lds16(const unsigned short* g, unsigned short* l) {
    __builtin_amdgcn_global_load_lds((gu16*)g, (lu16*)l, 16, 0, 0);
}

// ==========================================================================
// Shared GEMM core: 128x128 tile, BK=32, 256 thr = 4 waves (2x2),
// wave 64x64 (4x4 MFMA). global_load_lds width-16, unpadded [128][32] LDS.
// A [m][k] k-contig (lda), B [n][k] k-contig (ldb).
// ==========================================================================
__device__ __forceinline__ void gemm_core(
    const unsigned short* __restrict__ Ab, int lda,
    const unsigned short* __restrict__ Bb, int ldb,
    int K, f32x4 (&acc)[4][4],
    unsigned short* As, unsigned short* Bs)
{
    const int tid  = threadIdx.x;
    const int lane = tid & 63;
    const int wave = tid >> 6;
    const int wm   = (wave >> 1) * 64;
    const int wn   = (wave & 1) * 64;
    const int l16  = lane & 15;
    const int quad = lane >> 4;

    const int r0 = wave * 16 + (lane >> 2);
    const int c0 = (lane & 3) * 8;
    const unsigned short* gA0 = Ab + (long)r0 * lda + c0;
    const unsigned short* gA1 = gA0 + 64L * lda;
    const unsigned short* gB0 = Bb + (long)r0 * ldb + c0;
    const unsigned short* gB1 = gB0 + 64L * ldb;
    unsigned short* lA0 = As + wave * 512;
    unsigned short* lA1 = As + 2048 + wave * 512;
    unsigned short* lB0 = Bs + wave * 512;
    unsigned short* lB1 = Bs + 2048 + wave * 512;

    for (int k0 = 0; k0 < K; k0 += 32) {
        __syncthreads();
        gl_lds16(gA0 + k0, lA0);
        gl_lds16(gA1 + k0, lA1);
        gl_lds16(gB0 + k0, lB0);
        gl_lds16(gB1 + k0, lB1);
        __syncthreads();

        bf16x8 af[4], bfr[4];
        #pragma unroll
        for (int mi = 0; mi < 4; mi++)
            af[mi] = *(const bf16x8*)&As[(wm + mi * 16 + l16) * 32 + quad * 8];
        #pragma unroll
        for (int ni = 0; ni < 4; ni++)
            bfr[ni] = *(const bf16x8*)&Bs[(wn + ni * 16 + l16) * 32 + quad * 8];
        #pragma unroll
        for (int mi = 0; mi < 4; mi++)
            #pragma unroll
            for (int ni = 0; ni < 4; ni++)
                acc[mi][ni] = __builtin_amdgcn_mfma_f32_16x16x32_bf16(af[mi], bfr[ni], acc[mi][ni], 0, 0, 0);
    }
}

// ==========================================================================
// Generic GEMM kernel (S, AV, proj): optional trans-out / bias / residual
// ==========================================================================
template<typename OutT, bool TRANS_OUT, bool HAS_BIAS, bool HAS_RESID>
__global__ __launch_bounds__(256) void gemm_k(
    const unsigned short* __restrict__ Ag, long sA, int lda,
    const unsigned short* __restrict__ Bg, long sB, int ldb,
    OutT* __restrict__ Cg, long sC, int ldc,
    const float* __restrict__ bias,
    const float* __restrict__ resid, long sR,
    float alpha, int K)
{
    __shared__ __align__(16) unsigned short As[128 * 32];
    __shared__ __align__(16) unsigned short Bs[128 * 32];

    const unsigned short* Ab = Ag + (long)blockIdx.z * sA + (long)(blockIdx.y * 128) * lda;
    const unsigned short* Bb = Bg + (long)blockIdx.z * sB + (long)(blockIdx.x * 128) * ldb;

    f32x4 acc[4][4] = {};
    gemm_core(Ab, lda, Bb, ldb, K, acc, As, Bs);

    const int lane = threadIdx.x & 63;
    const int wave = threadIdx.x >> 6;
    const int l16  = lane & 15;
    const int quad = lane >> 4;
    const int mb = blockIdx.y * 128 + (wave >> 1) * 64;
    const int nb = blockIdx.x * 128 + (wave & 1) * 64;

    #pragma unroll
    for (int mi = 0; mi < 4; mi++) {
        #pragma unroll
        for (int ni = 0; ni < 4; ni++) {
            f32x4 v = acc[mi][ni];
            const int m0 = mb + mi * 16 + quad * 4;
            const int n  = nb + ni * 16 + l16;
            float o[4];
            #pragma unroll
            for (int r = 0; r < 4; r++) {
                float val = v[r] * alpha;
                if (HAS_BIAS) val += bias[m0 + r];
                o[r] = val;
            }
            if constexpr (!TRANS_OUT) {
                const long base = (long)blockIdx.z * sC;
                #pragma unroll
                for (int r = 0; r < 4; r++) {
                    float val = o[r];
                    if (HAS_RESID) val += resid[(long)blockIdx.z * sR + (long)(m0 + r) * ldc + n];
                    long idx = base + (long)(m0 + r) * ldc + n;
                    if constexpr (sizeof(OutT) == 2) ((unsigned short*)Cg)[idx] = f2bf(val);
                    else                              ((float*)Cg)[idx] = val;
                }
            } else {
                const long idx = (long)blockIdx.z * sC + (long)n * ldc + m0;
                if constexpr (sizeof(OutT) == 2) {
                    ushort4 p; p.x = f2bf(o[0]); p.y = f2bf(o[1]); p.z = f2bf(o[2]); p.w = f2bf(o[3]);
                    *(ushort4*)((unsigned short*)Cg + idx) = p;
                } else {
                    float4 p; p.x = o[0]; p.y = o[1]; p.z = o[2]; p.w = o[3];
                    *(float4*)((float*)Cg + idx) = p;
                }
            }
        }
    }
}

// ==========================================================================
// Fused QKV GEMM: A = Wqkv [1536][512] (wq|wk|wv rows), B = xnT [n][c].
// blockIdx.y 0..3 -> qT[i][c] (trans), 4..7 -> kT[j][c] (trans),
// 8..11 -> vB[c][j] (natural). bias = concatenated bqkv[1536].
// Grid (8, 12, 16) = 1536 blocks -> ~6 blocks/CU.
// ==========================================================================
__global__ __launch_bounds__(256) void qkv_k(
    const unsigned short* __restrict__ Wqkv,
    const unsigned short* __restrict__ xnT,
    unsigned short* __restrict__ qT,
    unsigned short* __restrict__ kT,
    unsigned short* __restrict__ vB,
    const float* __restrict__ bqkv)
{
    __shared__ __align__(16) unsigned short As[128 * 32];
    __shared__ __align__(16) unsigned short Bs[128 * 32];

    const unsigned short* Ab = Wqkv + (long)(blockIdx.y * 128) * 512;
    const unsigned short* Bb = xnT + (long)blockIdx.z * 524288 + (long)(blockIdx.x * 128) * 512;

    f32x4 acc[4][4] = {};
    gemm_core(Ab, 512, Bb, 512, 512, acc, As, Bs);

    const int lane = threadIdx.x & 63;
    const int wave = threadIdx.x >> 6;
    const int l16  = lane & 15;
    const int quad = lane >> 4;
    const int mb = blockIdx.y * 128 + (wave >> 1) * 64;   // global row in [0,1536)
    const int nb = blockIdx.x * 128 + (wave & 1) * 64;

    const int mat = blockIdx.y >> 2;                      // 0=q 1=k 2=v (block-uniform)
    const long zb = (long)blockIdx.z * 524288;

    #pragma unroll
    for (int mi = 0; mi < 4; mi++) {
        #pragma unroll
        for (int ni = 0; ni < 4; ni++) {
            f32x4 v = acc[mi][ni];
            const int m0 = mb + mi * 16 + quad * 4;       // global row
            const int n  = nb + ni * 16 + l16;
            float o[4];
            #pragma unroll
            for (int r = 0; r < 4; r++) o[r] = v[r] + bqkv[m0 + r];
            const int ml = m0 & 511;                      // row within matrix
            if (mat == 2) {
                // vB[c][j] natural
                #pragma unroll
                for (int r = 0; r < 4; r++)
                    vB[zb + (long)(ml + r) * 1024 + n] = f2bf(o[r]);
            } else {
                unsigned short* dst = (mat == 0) ? qT : kT;
                ushort4 p; p.x = f2bf(o[0]); p.y = f2bf(o[1]); p.z = f2bf(o[2]); p.w = f2bf(o[3]);
                *(ushort4*)(dst + zb + (long)n * 512 + ml) = p;
            }
        }
    }
}

// ==========================================================================
// Softmax over rows of S (bf16 [16][1024][1024], in place)
// ==========================================================================
__global__ __launch_bounds__(256) void softmax_k(unsigned short* __restrict__ S)
{
    __shared__ float red[4];
    const long row = (long)blockIdx.y * 1024 + blockIdx.x;
    unsigned short* sp = S + row * 1024;
    const int tid = threadIdx.x, lane = tid & 63, wv = tid >> 6;

    uint2 u = ((const uint2*)sp)[tid];
    float f0 = bf2f(u.x << 16), f1 = bf2f(u.x & 0xFFFF0000u);
    float f2 = bf2f(u.y << 16), f3 = bf2f(u.y & 0xFFFF0000u);

    float mx = fmaxf(fmaxf(f0, f1), fmaxf(f2, f3));
    for (int o = 32; o; o >>= 1) mx = fmaxf(mx, __shfl_down(mx, o));
    if (lane == 0) red[wv] = mx;
    __syncthreads();
    mx = fmaxf(fmaxf(red[0], red[1]), fmaxf(red[2], red[3]));

    float e0 = __expf(f0 - mx), e1 = __expf(f1 - mx);
    float e2 = __expf(f2 - mx), e3 = __expf(f3 - mx);
    float sum = (e0 + e1) + (e2 + e3);
    for (int o = 32; o; o >>= 1) sum += __shfl_down(sum, o);
    __syncthreads();
    if (lane == 0) red[wv] = sum;
    __syncthreads();
    const float inv = 1.f / (red[0] + red[1] + red[2] + red[3]);

    ushort4 o4;
    o4.x = f2bf(e0 * inv); o4.y = f2bf(e1 * inv);
    o4.z = f2bf(e2 * inv); o4.w = f2bf(e3 * inv);
    ((ushort4*)sp)[tid] = o4;
}

// ==========================================================================
// GroupNorm: x[b][c][n] (fp32) -> xnT[b][n][c] (bf16), 32 groups of 16 ch
// ==========================================================================
__global__ __launch_bounds__(256) void gn_k(
    const float* __restrict__ x, const float* __restrict__ gsc,
    const float* __restrict__ gbi, unsigned short* __restrict__ xnT)
{
    __shared__ __align__(16) unsigned short ln[16 * 1024];
    __shared__ float red[8];
    const int b = blockIdx.y, g = blockIdx.x;
    const int tid = threadIdx.x, lane = tid & 63, wv = tid >> 6;

    const float4* x4 = (const float4*)(x + ((long)b * 512 + g * 16) * 1024);
    float4 vals[16];
    float s = 0.f, ss = 0.f;
    #pragma unroll
    for (int i = 0; i < 16; i++) {
        float4 v = x4[tid + i * 256];
        vals[i] = v;
        s  += v.x + v.y + v.z + v.w;
        ss += v.x * v.x + v.y * v.y + v.z * v.z + v.w * v.w;
    }
    for (int o = 32; o; o >>= 1) { s += __shfl_down(s, o); ss += __shfl_down(ss, o); }
    if (lane == 0) { red[wv * 2] = s; red[wv * 2 + 1] = ss; }
    __syncthreads();
    const float S  = red[0] + red[2] + red[4] + red[6];
    const float SS = red[1] + red[3] + red[5] + red[7];
    const float mean = S * (1.f / 16384.f);
    const float var  = SS * (1.f / 16384.f) - mean * mean;
    const float inv  = rsqrtf(var + 1e-5f);

    #pragma unroll
    for (int i = 0; i < 16; i++) {
        const int idx = tid + i * 256;
        const int c   = idx >> 8;
        const float sc = gsc[g * 16 + c] * inv;
        const float bi = gbi[g * 16 + c] - mean * sc;
        float4 v = vals[i];
        ushort4 p;
        p.x = f2bf(v.x * sc + bi); p.y = f2bf(v.y * sc + bi);
        p.z = f2bf(v.z * sc + bi); p.w = f2bf(v.w * sc + bi);
        ((ushort4*)ln)[idx] = p;
    }
    __syncthreads();

    unsigned short* op = xnT + (long)b * 1024 * 512 + g * 16;
    for (int rep = 0; rep < 4; rep++) {
        const int n = rep * 256 + tid;
        union { unsigned short u[16]; uint4 v[2]; } t;
        #pragma unroll
        for (int c = 0; c < 16; c++) t.u[c] = ln[c * 1024 + n];
        *(uint4*)&op[(long)n * 512]     = t.v[0];
        *(uint4*)&op[(long)n * 512 + 8] = t.v[1];
    }
}

// ---------- weights fp32 -> bf16 + bias concat (y==4 path) ----------
__global__ __launch_bounds__(256) void wconv_k(
    const float* __restrict__ w0, const float* __restrict__ w1,
    const float* __restrict__ w2, const float* __restrict__ w3,
    const float* __restrict__ b0, const float* __restrict__ b1,
    const float* __restrict__ b2,
    unsigned short* __restrict__ out, float* __restrict__ bqkv)
{
    const int m = blockIdx.y;
    const int i = blockIdx.x * 256 + threadIdx.x;
    if (m == 4) {
        if (i < 384) {   // 1536 floats = 384 float4
            const int which = i >> 7, off = i & 127;
            const float* src = (which == 0) ? b0 : (which == 1) ? b1 : b2;
            ((float4*)bqkv)[i] = ((const float4*)src)[off];
        }
        return;
    }
    const float* src = (m == 0) ? w0 : (m == 1) ? w1 : (m == 2) ? w2 : w3;
    float4 v = ((const float4*)src)[i];
    ushort4 o; o.x = f2bf(v.x); o.y = f2bf(v.y); o.z = f2bf(v.z); o.w = f2bf(v.w);
    ((ushort4*)(out + (long)m * 262144))[i] = o;
}

// ==========================================================================
extern "C" void kernel_launch(void* const* d_in, const int* in_sizes, int n_in,
                              void* d_out, int out_size, void* d_ws, size_t ws_size,
                              hipStream_t stream)
{
    const float* x   = (const float*)d_in[0];
    const float* gsc = (const float*)d_in[1];
    const float* gbi = (const float*)d_in[2];
    const float* wq  = (const float*)d_in[3];
    const float* bq  = (const float*)d_in[4];
    const float* wk  = (const float*)d_in[5];
    const float* bk  = (const float*)d_in[6];
    const float* wv  = (const float*)d_in[7];
    const float* bv  = (const float*)d_in[8];
    const float* wp  = (const float*)d_in[9];
    const float* bp  = (const float*)d_in[10];
    float* out = (float*)d_out;

    char* ws = (char*)d_ws;
    unsigned short* xnT = (unsigned short*)(ws);               // 16 MB [b][n][c]; reused as OT
    unsigned short* qT  = (unsigned short*)(ws + 16777216);    // 16 MB [b][i][c]
    unsigned short* kT  = (unsigned short*)(ws + 33554432);    // 16 MB [b][j][c]
    unsigned short* vB  = (unsigned short*)(ws + 50331648);    // 16 MB [b][c][j]
    unsigned short* Sb  = (unsigned short*)(ws + 67108864);    // 32 MB [b][i][j] bf16
    unsigned short* Wb  = (unsigned short*)(ws + 100663296);   // 2 MB: wq|wk|wv|wp bf16
    float*          bqkv= (float*)        (ws + 102760448);    // 6 KB
    unsigned short* OT  = xnT;

    const long sBCN = 512L * 1024;

    wconv_k<<<dim3(256, 5), 256, 0, stream>>>(wq, wk, wv, wp, bq, bk, bv, Wb, bqkv);
    gn_k<<<dim3(32, 16), 256, 0, stream>>>(x, gsc, gbi, xnT);

    // fused QKV: qT[i][c], kT[j][c], vB[c][j]
    qkv_k<<<dim3(8, 12, 16), 256, 0, stream>>>(Wb, xnT, qT, kT, vB, bqkv);

    // S[i][j] = (1/sqrt(512)) * q·k -> bf16
    gemm_k<unsigned short, false, false, false><<<dim3(8, 8, 16), 256, 0, stream>>>(
        qT, sBCN, 512, kT, sBCN, 512, Sb, 1048576L, 1024, nullptr, nullptr, 0,
        0.044194173824159216f, 512);
    softmax_k<<<dim3(1024, 16), 256, 0, stream>>>(Sb);
    // O[c][i] = sum_j v[c][j]*A[i][j] -> OT[i][c]
    gemm_k<unsigned short, true, false, false><<<dim3(8, 4, 16), 256, 0, stream>>>(
        vB, sBCN, 1024, Sb, 1048576L, 1024, OT, sBCN, 512,
        nullptr, nullptr, 0, 1.f, 1024);
    // out = Wp * O + bp + x
    gemm_k<float, false, true, true><<<dim3(8, 4, 16), 256, 0, stream>>>(
        Wb + 786432, 0, 512, OT, sBCN, 512, out, sBCN, 1024, bp, x, sBCN, 1.f, 512);
}

// Round 5
// 242.825 us; speedup vs baseline: 1.2769x; 1.0671x over previous
//
#include <hip/hip_runtime.h>

// ---------- types ----------
typedef __bf16 bf16x8 __attribute__((ext_vector_type(8)));
typedef float  f32x4  __attribute__((ext_vector_type(4)));

__device__ __forceinline__ unsigned short f2bf(float f) {
    union { float f; unsigned int u; } x; x.f = f;
    unsigned int r = (x.u + 0x7FFFu + ((x.u >> 16) & 1u)) >> 16;  // RNE
    return (unsigned short)r;
}
__device__ __forceinline__ float bf2f(unsigned int hi) {
    union { unsigned int u; float f; } x; x.u = hi; return x.f;
}

// async global->LDS, 16B per lane; LDS dst is wave-uniform base + lane*16
typedef const __attribute__((address_space(1))) unsigned short gu16;
typedef __attribute__((address_space(3)))       unsigned short lu16;
__device__ __forceinline__ void gl_lds16(const unsigned short* g, unsigned short* l) {
    __builtin_amdgcn_global_load_lds((gu16*)g, (lu16*)l, 16, 0, 0);
}

// ==========================================================================
// GEMM core: 128x128 tile, BK=64 as TWO BK=32 panels per barrier pair
// (panel layout keeps 64-B LDS row stride — conflict-free; a flat 128-B
// stride row would put all 16 lanes of a quad on the same banks).
// 256 thr = 4 waves (2x2), wave 64x64 (4x4 MFMA 16x16x32).
// A [m][k] k-contig (lda), B [n][k] k-contig (ldb). K % 64 == 0.
// LDS: As/Bs 16 KB each (two 128x32 panels).
// ==========================================================================
__device__ __forceinline__ void gemm_core(
    const unsigned short* __restrict__ Ab, int lda,
    const unsigned short* __restrict__ Bb, int ldb,
    int K, f32x4 (&acc)[4][4],
    unsigned short* As, unsigned short* Bs)
{
    const int tid  = threadIdx.x;
    const int lane = tid & 63;
    const int wave = tid >> 6;
    const int wm   = (wave >> 1) * 64;
    const int wn   = (wave & 1) * 64;
    const int l16  = lane & 15;
    const int quad = lane >> 4;

    // BK=32 panel staging map: p = wave*64 + lane (16B units); row=p/4, col=(p%4)*8
    const int r0 = wave * 16 + (lane >> 2);
    const int c0 = (lane & 3) * 8;
    const unsigned short* gA0 = Ab + (long)r0 * lda + c0;
    const unsigned short* gA1 = gA0 + 64L * lda;
    const unsigned short* gB0 = Bb + (long)r0 * ldb + c0;
    const unsigned short* gB1 = gB0 + 64L * ldb;
    unsigned short* lA0 = As + wave * 512;           // panel0, rows 0-63
    unsigned short* lA1 = As + 2048 + wave * 512;    // panel0, rows 64-127
    unsigned short* lB0 = Bs + wave * 512;
    unsigned short* lB1 = Bs + 2048 + wave * 512;

    for (int k0 = 0; k0 < K; k0 += 64) {
        __syncthreads();
        gl_lds16(gA0 + k0, lA0);
        gl_lds16(gA1 + k0, lA1);
        gl_lds16(gB0 + k0, lB0);
        gl_lds16(gB1 + k0, lB1);
        gl_lds16(gA0 + k0 + 32, lA0 + 4096);         // panel1
        gl_lds16(gA1 + k0 + 32, lA1 + 4096);
        gl_lds16(gB0 + k0 + 32, lB0 + 4096);
        gl_lds16(gB1 + k0 + 32, lB1 + 4096);
        __syncthreads();

        #pragma unroll
        for (int pan = 0; pan < 2; pan++) {
            const unsigned short* Ap = As + pan * 4096;
            const unsigned short* Bp = Bs + pan * 4096;
            bf16x8 af[4], bfr[4];
            #pragma unroll
            for (int mi = 0; mi < 4; mi++)
                af[mi] = *(const bf16x8*)&Ap[(wm + mi * 16 + l16) * 32 + quad * 8];
            #pragma unroll
            for (int ni = 0; ni < 4; ni++)
                bfr[ni] = *(const bf16x8*)&Bp[(wn + ni * 16 + l16) * 32 + quad * 8];
            #pragma unroll
            for (int mi = 0; mi < 4; mi++)
                #pragma unroll
                for (int ni = 0; ni < 4; ni++)
                    acc[mi][ni] = __builtin_amdgcn_mfma_f32_16x16x32_bf16(af[mi], bfr[ni], acc[mi][ni], 0, 0, 0);
        }
    }
}

// ==========================================================================
// Generic GEMM kernel (S, AV, proj): optional trans-out / bias / residual
// ==========================================================================
template<typename OutT, bool TRANS_OUT, bool HAS_BIAS, bool HAS_RESID>
__global__ __launch_bounds__(256) void gemm_k(
    const unsigned short* __restrict__ Ag, long sA, int lda,
    const unsigned short* __restrict__ Bg, long sB, int ldb,
    OutT* __restrict__ Cg, long sC, int ldc,
    const float* __restrict__ bias,
    const float* __restrict__ resid, long sR,
    float alpha, int K)
{
    __shared__ __align__(16) unsigned short As[128 * 64];   // 16 KB (2 panels)
    __shared__ __align__(16) unsigned short Bs[128 * 64];

    const unsigned short* Ab = Ag + (long)blockIdx.z * sA + (long)(blockIdx.y * 128) * lda;
    const unsigned short* Bb = Bg + (long)blockIdx.z * sB + (long)(blockIdx.x * 128) * ldb;

    f32x4 acc[4][4] = {};
    gemm_core(Ab, lda, Bb, ldb, K, acc, As, Bs);

    const int lane = threadIdx.x & 63;
    const int wave = threadIdx.x >> 6;
    const int l16  = lane & 15;
    const int quad = lane >> 4;
    const int mb = blockIdx.y * 128 + (wave >> 1) * 64;
    const int nb = blockIdx.x * 128 + (wave & 1) * 64;

    #pragma unroll
    for (int mi = 0; mi < 4; mi++) {
        #pragma unroll
        for (int ni = 0; ni < 4; ni++) {
            f32x4 v = acc[mi][ni];
            const int m0 = mb + mi * 16 + quad * 4;
            const int n  = nb + ni * 16 + l16;
            float o[4];
            #pragma unroll
            for (int r = 0; r < 4; r++) {
                float val = v[r] * alpha;
                if (HAS_BIAS) val += bias[m0 + r];
                o[r] = val;
            }
            if constexpr (!TRANS_OUT) {
                const long base = (long)blockIdx.z * sC;
                #pragma unroll
                for (int r = 0; r < 4; r++) {
                    float val = o[r];
                    if (HAS_RESID) val += resid[(long)blockIdx.z * sR + (long)(m0 + r) * ldc + n];
                    long idx = base + (long)(m0 + r) * ldc + n;
                    if constexpr (sizeof(OutT) == 2) ((unsigned short*)Cg)[idx] = f2bf(val);
                    else                              ((float*)Cg)[idx] = val;
                }
            } else {
                const long idx = (long)blockIdx.z * sC + (long)n * ldc + m0;
                if constexpr (sizeof(OutT) == 2) {
                    ushort4 p; p.x = f2bf(o[0]); p.y = f2bf(o[1]); p.z = f2bf(o[2]); p.w = f2bf(o[3]);
                    *(ushort4*)((unsigned short*)Cg + idx) = p;
                } else {
                    float4 p; p.x = o[0]; p.y = o[1]; p.z = o[2]; p.w = o[3];
                    *(float4*)((float*)Cg + idx) = p;
                }
            }
        }
    }
}

// ==========================================================================
// Fused QKV GEMM: A = Wqkv [1536][512] (wq|wk|wv rows), B = xnT [n][c].
// blockIdx.y 0..3 -> qT[i][c] (trans), 4..7 -> kT[j][c] (trans),
// 8..11 -> vB[c][j] (natural). Grid (8, 12, 16) = 1536 blocks.
// ==========================================================================
__global__ __launch_bounds__(256) void qkv_k(
    const unsigned short* __restrict__ Wqkv,
    const unsigned short* __restrict__ xnT,
    unsigned short* __restrict__ qT,
    unsigned short* __restrict__ kT,
    unsigned short* __restrict__ vB,
    const float* __restrict__ bqkv)
{
    __shared__ __align__(16) unsigned short As[128 * 64];
    __shared__ __align__(16) unsigned short Bs[128 * 64];

    const unsigned short* Ab = Wqkv + (long)(blockIdx.y * 128) * 512;
    const unsigned short* Bb = xnT + (long)blockIdx.z * 524288 + (long)(blockIdx.x * 128) * 512;

    f32x4 acc[4][4] = {};
    gemm_core(Ab, 512, Bb, 512, 512, acc, As, Bs);

    const int lane = threadIdx.x & 63;
    const int wave = threadIdx.x >> 6;
    const int l16  = lane & 15;
    const int quad = lane >> 4;
    const int mb = blockIdx.y * 128 + (wave >> 1) * 64;   // global row in [0,1536)
    const int nb = blockIdx.x * 128 + (wave & 1) * 64;

    const int mat = blockIdx.y >> 2;                      // 0=q 1=k 2=v (block-uniform)
    const long zb = (long)blockIdx.z * 524288;

    #pragma unroll
    for (int mi = 0; mi < 4; mi++) {
        #pragma unroll
        for (int ni = 0; ni < 4; ni++) {
            f32x4 v = acc[mi][ni];
            const int m0 = mb + mi * 16 + quad * 4;       // global row
            const int n  = nb + ni * 16 + l16;
            float o[4];
            #pragma unroll
            for (int r = 0; r < 4; r++) o[r] = v[r] + bqkv[m0 + r];
            const int ml = m0 & 511;                      // row within matrix
            if (mat == 2) {
                #pragma unroll
                for (int r = 0; r < 4; r++)
                    vB[zb + (long)(ml + r) * 1024 + n] = f2bf(o[r]);
            } else {
                unsigned short* dst = (mat == 0) ? qT : kT;
                ushort4 p; p.x = f2bf(o[0]); p.y = f2bf(o[1]); p.z = f2bf(o[2]); p.w = f2bf(o[3]);
                *(ushort4*)(dst + zb + (long)n * 512 + ml) = p;
            }
        }
    }
}

// ==========================================================================
// Softmax: one WAVE per row (no barriers, no LDS). 4 rows/block.
// S bf16 [16][1024][1024] in place. 16 elems/lane = 2x uint4.
// ==========================================================================
__global__ __launch_bounds__(256) void softmax_k(unsigned short* __restrict__ S)
{
    const int wv   = threadIdx.x >> 6;
    const int lane = threadIdx.x & 63;
    const long row = (long)blockIdx.y * 1024 + blockIdx.x * 4 + wv;
    unsigned short* sp = S + row * 1024;

    uint4 u0 = ((const uint4*)sp)[lane];
    uint4 u1 = ((const uint4*)sp)[lane + 64];

    float f[16];
    const unsigned int* up = (const unsigned int*)&u0;
    #pragma unroll
    for (int i = 0; i < 4; i++) {
        f[2 * i]     = bf2f(up[i] << 16);
        f[2 * i + 1] = bf2f(up[i] & 0xFFFF0000u);
    }
    up = (const unsigned int*)&u1;
    #pragma unroll
    for (int i = 0; i < 4; i++) {
        f[8 + 2 * i] = bf2f(up[i] << 16);
        f[9 + 2 * i] = bf2f(up[i] & 0xFFFF0000u);
    }

    float mx = f[0];
    #pragma unroll
    for (int i = 1; i < 16; i++) mx = fmaxf(mx, f[i]);
    #pragma unroll
    for (int o = 1; o < 64; o <<= 1) mx = fmaxf(mx, __shfl_xor(mx, o));

    float sum = 0.f;
    #pragma unroll
    for (int i = 0; i < 16; i++) { f[i] = __expf(f[i] - mx); sum += f[i]; }
    #pragma unroll
    for (int o = 1; o < 64; o <<= 1) sum += __shfl_xor(sum, o);
    const float inv = 1.f / sum;

    uint4 w0, w1;
    unsigned int* wp = (unsigned int*)&w0;
    #pragma unroll
    for (int i = 0; i < 4; i++)
        wp[i] = (unsigned int)f2bf(f[2 * i] * inv) | ((unsigned int)f2bf(f[2 * i + 1] * inv) << 16);
    wp = (unsigned int*)&w1;
    #pragma unroll
    for (int i = 0; i < 4; i++)
        wp[i] = (unsigned int)f2bf(f[8 + 2 * i] * inv) | ((unsigned int)f2bf(f[9 + 2 * i] * inv) << 16);

    ((uint4*)sp)[lane]      = w0;
    ((uint4*)sp)[lane + 64] = w1;
}

// ==========================================================================
// GroupNorm: x[b][c][n] (fp32) -> xnT[b][n][c] (bf16), 32 groups of 16 ch
// ==========================================================================
__global__ __launch_bounds__(256) void gn_k(
    const float* __restrict__ x, const float* __restrict__ gsc,
    const float* __restrict__ gbi, unsigned short* __restrict__ xnT)
{
    __shared__ __align__(16) unsigned short ln[16 * 1024];
    __shared__ float red[8];
    const int b = blockIdx.y, g = blockIdx.x;
    const int tid = threadIdx.x, lane = tid & 63, wv = tid >> 6;

    const float4* x4 = (const float4*)(x + ((long)b * 512 + g * 16) * 1024);
    float4 vals[16];
    float s = 0.f, ss = 0.f;
    #pragma unroll
    for (int i = 0; i < 16; i++) {
        float4 v = x4[tid + i * 256];
        vals[i] = v;
        s  += v.x + v.y + v.z + v.w;
        ss += v.x * v.x + v.y * v.y + v.z * v.z + v.w * v.w;
    }
    for (int o = 32; o; o >>= 1) { s += __shfl_down(s, o); ss += __shfl_down(ss, o); }
    if (lane == 0) { red[wv * 2] = s; red[wv * 2 + 1] = ss; }
    __syncthreads();
    const float S  = red[0] + red[2] + red[4] + red[6];
    const float SS = red[1] + red[3] + red[5] + red[7];
    const float mean = S * (1.f / 16384.f);
    const float var  = SS * (1.f / 16384.f) - mean * mean;
    const float inv  = rsqrtf(var + 1e-5f);

    #pragma unroll
    for (int i = 0; i < 16; i++) {
        const int idx = tid + i * 256;
        const int c   = idx >> 8;
        const float sc = gsc[g * 16 + c] * inv;
        const float bi = gbi[g * 16 + c] - mean * sc;
        float4 v = vals[i];
        ushort4 p;
        p.x = f2bf(v.x * sc + bi); p.y = f2bf(v.y * sc + bi);
        p.z = f2bf(v.z * sc + bi); p.w = f2bf(v.w * sc + bi);
        ((ushort4*)ln)[idx] = p;
    }
    __syncthreads();

    unsigned short* op = xnT + (long)b * 1024 * 512 + g * 16;
    for (int rep = 0; rep < 4; rep++) {
        const int n = rep * 256 + tid;
        union { unsigned short u[16]; uint4 v[2]; } t;
        #pragma unroll
        for (int c = 0; c < 16; c++) t.u[c] = ln[c * 1024 + n];
        *(uint4*)&op[(long)n * 512]     = t.v[0];
        *(uint4*)&op[(long)n * 512 + 8] = t.v[1];
    }
}

// ---------- weights fp32 -> bf16 + bias concat (y==4 path) ----------
__global__ __launch_bounds__(256) void wconv_k(
    const float* __restrict__ w0, const float* __restrict__ w1,
    const float* __restrict__ w2, const float* __restrict__ w3,
    const float* __restrict__ b0, const float* __restrict__ b1,
    const float* __restrict__ b2,
    unsigned short* __restrict__ out, float* __restrict__ bqkv)
{
    const int m = blockIdx.y;
    const int i = blockIdx.x * 256 + threadIdx.x;
    if (m == 4) {
        if (i < 384) {
            const int which = i >> 7, off = i & 127;
            const float* src = (which == 0) ? b0 : (which == 1) ? b1 : b2;
            ((float4*)bqkv)[i] = ((const float4*)src)[off];
        }
        return;
    }
    const float* src = (m == 0) ? w0 : (m == 1) ? w1 : (m == 2) ? w2 : w3;
    float4 v = ((const float4*)src)[i];
    ushort4 o; o.x = f2bf(v.x); o.y = f2bf(v.y); o.z = f2bf(v.z); o.w = f2bf(v.w);
    ((ushort4*)(out + (long)m * 262144))[i] = o;
}

// ==========================================================================
extern "C" void kernel_launch(void* const* d_in, const int* in_sizes, int n_in,
                              void* d_out, int out_size, void* d_ws, size_t ws_size,
                              hipStream_t stream)
{
    const float* x   = (const float*)d_in[0];
    const float* gsc = (const float*)d_in[1];
    const float* gbi = (const float*)d_in[2];
    const float* wq  = (const float*)d_in[3];
    const float* bq  = (const float*)d_in[4];
    const float* wk  = (const float*)d_in[5];
    const float* bk  = (const float*)d_in[6];
    const float* wv  = (const float*)d_in[7];
    const float* bv  = (const float*)d_in[8];
    const float* wp  = (const float*)d_in[9];
    const float* bp  = (const float*)d_in[10];
    float* out = (float*)d_out;

    char* ws = (char*)d_ws;
    unsigned short* xnT = (unsigned short*)(ws);               // 16 MB [b][n][c]; reused as OT
    unsigned short* qT  = (unsigned short*)(ws + 16777216);    // 16 MB [b][i][c]
    unsigned short* kT  = (unsigned short*)(ws + 33554432);    // 16 MB [b][j][c]
    unsigned short* vB  = (unsigned short*)(ws + 50331648);    // 16 MB [b][c][j]
    unsigned short* Sb  = (unsigned short*)(ws + 67108864);    // 32 MB [b][i][j] bf16
    unsigned short* Wb  = (unsigned short*)(ws + 100663296);   // 2 MB: wq|wk|wv|wp bf16
    float*          bqkv= (float*)        (ws + 102760448);    // 6 KB
    unsigned short* OT  = xnT;

    const long sBCN = 512L * 1024;

    wconv_k<<<dim3(256, 5), 256, 0, stream>>>(wq, wk, wv, wp, bq, bk, bv, Wb, bqkv);
    gn_k<<<dim3(32, 16), 256, 0, stream>>>(x, gsc, gbi, xnT);

    // fused QKV: qT[i][c], kT[j][c], vB[c][j]
    qkv_k<<<dim3(8, 12, 16), 256, 0, stream>>>(Wb, xnT, qT, kT, vB, bqkv);

    // S[i][j] = (1/sqrt(512)) * q·k -> bf16
    gemm_k<unsigned short, false, false, false><<<dim3(8, 8, 16), 256, 0, stream>>>(
        qT, sBCN, 512, kT, sBCN, 512, Sb, 1048576L, 1024, nullptr, nullptr, 0,
        0.044194173824159216f, 512);
    softmax_k<<<dim3(256, 16), 256, 0, stream>>>(Sb);
    // O[c][i] = sum_j v[c][j]*A[i][j] -> OT[i][c]
    gemm_k<unsigned short, true, false, false><<<dim3(8, 4, 16), 256, 0, stream>>>(
        vB, sBCN, 1024, Sb, 1048576L, 1024, OT, sBCN, 512,
        nullptr, nullptr, 0, 1.f, 1024);
    // out = Wp * O + bp + x
    gemm_k<float, false, true, true><<<dim3(8, 4, 16), 256, 0, stream>>>(
        Wb + 786432, 0, 512, OT, sBCN, 512, out, sBCN, 1024, bp, x, sBCN, 1.f, 512);
}